// Round 1
// baseline (176.897 us; speedup 1.0000x reference)
//
#include <hip/hip_runtime.h>
#include <math.h>

#define BB 32
#define CC 768
#define HID 96
#define NPIX 1024
#define KSEL 256
#define BN_EPS_F 1e-5f

// ---------------------------------------------------------------------------
// K1: per-batch GEMM  H[o,n] = sum_c w1[o,c] * x[b,c,n], fused BN + ReLU.
// grid (16, 32): x = n-tile (64 wide), y = batch. 256 threads.
// Thread tile: 4 n x 6 o (acc[6][4]).
// ---------------------------------------------------------------------------
__global__ __launch_bounds__(256) void k1_gemm_bn_relu(
    const float* __restrict__ x, const float* __restrict__ w1,
    const float* __restrict__ gamma, const float* __restrict__ beta,
    const float* __restrict__ mean, const float* __restrict__ var,
    float* __restrict__ h_out)
{
    __shared__ float Xs[64][68];   // [c-chunk][n-tile], padded
    __shared__ float Ws[64][97];   // [c-chunk][o], padded (stride 97 -> conflict-light)
    __shared__ float scale_s[HID], shift_s[HID];

    const int t  = threadIdx.x;
    const int b  = blockIdx.y;
    const int n0 = blockIdx.x * 64;
    const int tx = t & 15;   // n group: 4 floats at tx*4
    const int ty = t >> 4;   // o group: o = ty + 16*j, j=0..5

    if (t < HID) {
        float sc = gamma[t] * rsqrtf(var[t] + BN_EPS_F);
        scale_s[t] = sc;
        shift_s[t] = beta[t] - mean[t] * sc;
    }

    float acc[6][4];
#pragma unroll
    for (int j = 0; j < 6; ++j)
#pragma unroll
        for (int i = 0; i < 4; ++i) acc[j][i] = 0.f;

    const float* xb = x + (size_t)b * CC * NPIX + n0;

    for (int c0 = 0; c0 < CC; c0 += 64) {
        __syncthreads();
        // stage X tile: 64 c-rows x 64 floats
        {
            int cc = t >> 2, q = t & 3;
            const float* src = xb + (size_t)(c0 + cc) * NPIX;
#pragma unroll
            for (int i = 0; i < 4; ++i) {
                int f4 = q + 4 * i;  // 0..15
                float4 v = *reinterpret_cast<const float4*>(src + f4 * 4);
                *reinterpret_cast<float4*>(&Xs[cc][f4 * 4]) = v;
            }
        }
        // stage W tile transposed: Ws[cc][o] = w1[o, c0+cc]
        for (int idx = t; idx < HID * 64; idx += 256) {
            int o = idx >> 6, cc = idx & 63;
            Ws[cc][o] = w1[(size_t)o * CC + c0 + cc];
        }
        __syncthreads();

#pragma unroll 4
        for (int cc = 0; cc < 64; ++cc) {
            float4 xv = *reinterpret_cast<const float4*>(&Xs[cc][tx * 4]);
#pragma unroll
            for (int j = 0; j < 6; ++j) {
                float w = Ws[cc][ty + 16 * j];
                acc[j][0] += w * xv.x;
                acc[j][1] += w * xv.y;
                acc[j][2] += w * xv.z;
                acc[j][3] += w * xv.w;
            }
        }
    }

    // epilogue: BN + ReLU, store
#pragma unroll
    for (int j = 0; j < 6; ++j) {
        int o = ty + 16 * j;
        float sc = scale_s[o], sh = shift_s[o];
        float4 r;
        r.x = fmaxf(acc[j][0] * sc + sh, 0.f);
        r.y = fmaxf(acc[j][1] * sc + sh, 0.f);
        r.z = fmaxf(acc[j][2] * sc + sh, 0.f);
        r.w = fmaxf(acc[j][3] * sc + sh, 0.f);
        *reinterpret_cast<float4*>(
            &h_out[((size_t)b * HID + o) * NPIX + n0 + tx * 4]) = r;
    }
}

// ---------------------------------------------------------------------------
// K2: 3x3 conv HID->1, SAME zero pad. grid 32 (one block per batch), 256 thr.
// ---------------------------------------------------------------------------
__global__ __launch_bounds__(256) void k2_conv3x3(
    const float* __restrict__ h_in, const float* __restrict__ w2,
    const float* __restrict__ b2, float* __restrict__ score_out)
{
    __shared__ float hs[34][36];
    __shared__ float w2s[HID][9];

    const int t = threadIdx.x, b = blockIdx.x;

    for (int i = t; i < 34 * 36; i += 256) ((float*)hs)[i] = 0.f;
    for (int i = t; i < HID * 9; i += 256) ((float*)w2s)[i] = w2[i];

    float accp[4] = {0.f, 0.f, 0.f, 0.f};
    const float* hb = h_in + (size_t)b * HID * NPIX;

    for (int o = 0; o < HID; ++o) {
        __syncthreads();
#pragma unroll
        for (int i = 0; i < 4; ++i) {
            int n = t + i * 256, y = n >> 5, xx = n & 31;
            hs[y + 1][xx + 1] = hb[o * NPIX + n];
        }
        __syncthreads();
#pragma unroll
        for (int i = 0; i < 4; ++i) {
            int n = t + i * 256, y = n >> 5, xx = n & 31;
            float s = 0.f;
#pragma unroll
            for (int ky = 0; ky < 3; ++ky)
#pragma unroll
                for (int kx = 0; kx < 3; ++kx)
                    s += hs[y + ky][xx + kx] * w2s[o][ky * 3 + kx];
            accp[i] += s;
        }
    }
    float bb = b2[0];
#pragma unroll
    for (int i = 0; i < 4; ++i) {
        int n = t + i * 256;
        score_out[b * NPIX + n] = accp[i] + bb;
    }
}

// ---------------------------------------------------------------------------
// K3: per-row exact top-256 (radix select on sortable uint, first-index
// tie-break == jax.lax.top_k) + softmax -> dense weight[1024].
// grid 32, 256 threads.
// ---------------------------------------------------------------------------
__global__ __launch_bounds__(256) void k3_topk_softmax(
    const float* __restrict__ score, float* __restrict__ weight)
{
    __shared__ unsigned us[NPIX];
    __shared__ float    fs[NPIX];
    __shared__ unsigned hist[256];
    __shared__ unsigned sh_bin, sh_rem;
    __shared__ unsigned pcnt[4];
    __shared__ unsigned eq_base;
    __shared__ float    redf[4];
    __shared__ float    sh_max, sh_sum;

    const int t = threadIdx.x, b = blockIdx.x;
    const int lane = t & 63, wv = t >> 6;

#pragma unroll
    for (int i = 0; i < 4; ++i) {
        int n = t + 256 * i;
        float f = score[b * NPIX + n];
        fs[n] = f;
        unsigned u = __float_as_uint(f);
        u = (u & 0x80000000u) ? ~u : (u | 0x80000000u);  // order-preserving
        us[n] = u;
    }
    if (t == 0) eq_base = 0;

    unsigned prefix = 0, rem = KSEL;
    for (int p = 3; p >= 0; --p) {
        hist[t] = 0;
        __syncthreads();
        const int sh_hi = (p + 1) * 8;
#pragma unroll
        for (int i = 0; i < 4; ++i) {
            unsigned u = us[t + 256 * i];
            bool match = (p == 3) || ((u >> sh_hi) == (prefix >> sh_hi));
            if (match) atomicAdd(&hist[(u >> (p * 8)) & 0xffu], 1u);
        }
        __syncthreads();
        // inclusive suffix-sum: hist[i] = count with byte >= i (among matches)
        for (int step = 1; step < 256; step <<= 1) {
            unsigned vv = (t + step < 256) ? hist[t + step] : 0u;
            __syncthreads();
            hist[t] += vv;
            __syncthreads();
        }
        if (hist[t] >= rem && (t == 255 || hist[t + 1] < rem)) {
            sh_bin = (unsigned)t;
            sh_rem = rem - ((t == 255) ? 0u : hist[t + 1]);
        }
        __syncthreads();
        prefix |= (sh_bin << (p * 8));
        rem = sh_rem;
        __syncthreads();
    }
    const unsigned T = prefix;       // exact K-th largest (as sortable uint)
    const unsigned need = rem;       // how many ==T to take (first by index)

    // row max (= top-1) for softmax stability
    float m = -INFINITY;
#pragma unroll
    for (int i = 0; i < 4; ++i) m = fmaxf(m, fs[t + 256 * i]);
#pragma unroll
    for (int off = 32; off >= 1; off >>= 1) m = fmaxf(m, __shfl_xor(m, off));
    if (lane == 0) redf[wv] = m;
    __syncthreads();
    if (t == 0) sh_max = fmaxf(fmaxf(redf[0], redf[1]), fmaxf(redf[2], redf[3]));
    __syncthreads();
    m = sh_max;

    float sumExp = 0.f;
    for (int i = 0; i < 4; ++i) {         // rounds in ascending index order
        int n = i * 256 + t;
        unsigned u = us[n];
        bool eq = (u == T);
        unsigned long long mask = __ballot(eq);
        unsigned lp = __popcll(mask & ((1ULL << lane) - 1ULL));
        if (lane == 0) pcnt[wv] = (unsigned)__popcll(mask);
        __syncthreads();
        unsigned wave_prefix = eq_base;
        for (int w = 0; w < wv; ++w) wave_prefix += pcnt[w];
        unsigned rank = wave_prefix + lp;
        bool sel = (u > T) || (eq && rank < need);
        float e = sel ? expf(fs[n] - m) : 0.f;
        fs[n] = e;
        sumExp += e;
        __syncthreads();
        if (t == 0) eq_base += pcnt[0] + pcnt[1] + pcnt[2] + pcnt[3];
        __syncthreads();
    }
#pragma unroll
    for (int off = 32; off >= 1; off >>= 1) sumExp += __shfl_xor(sumExp, off);
    if (lane == 0) redf[wv] = sumExp;
    __syncthreads();
    if (t == 0) sh_sum = redf[0] + redf[1] + redf[2] + redf[3];
    __syncthreads();
    const float inv = 1.0f / sh_sum;
#pragma unroll
    for (int i = 0; i < 4; ++i) {
        int n = i * 256 + t;
        weight[b * NPIX + n] = fs[n] * inv;
    }
}

// ---------------------------------------------------------------------------
// K4: v[b,c] = sum_n x[b,c,n] * weight[b,n]. grid 32*192, 256 thr (4 waves,
// one c per wave), fully coalesced float4 reads.
// ---------------------------------------------------------------------------
__global__ __launch_bounds__(256) void k4_weighted_sum(
    const float* __restrict__ x, const float* __restrict__ weight,
    float* __restrict__ v)
{
    __shared__ float wsm[NPIX];
    const int t = threadIdx.x;
    const int b = blockIdx.x / 192, cg = blockIdx.x % 192;

    *reinterpret_cast<float4*>(&wsm[t * 4]) =
        *reinterpret_cast<const float4*>(&weight[b * NPIX + t * 4]);
    __syncthreads();

    const int lane = t & 63, wv = t >> 6;
    const int c = cg * 4 + wv;
    const float* xr = x + ((size_t)b * CC + c) * NPIX;

    float acc = 0.f;
#pragma unroll
    for (int j = 0; j < 4; ++j) {
        int off = j * 256 + lane * 4;
        float4 xv = *reinterpret_cast<const float4*>(xr + off);
        float4 wv4 = *reinterpret_cast<const float4*>(&wsm[off]);
        acc += xv.x * wv4.x + xv.y * wv4.y + xv.z * wv4.z + xv.w * wv4.w;
    }
#pragma unroll
    for (int off = 32; off >= 1; off >>= 1) acc += __shfl_xor(acc, off);
    if (lane == 0) v[(size_t)b * CC + c] = acc;
}

// ---------------------------------------------------------------------------
extern "C" void kernel_launch(void* const* d_in, const int* in_sizes, int n_in,
                              void* d_out, int out_size, void* d_ws, size_t ws_size,
                              hipStream_t stream)
{
    const float* x     = (const float*)d_in[0];
    const float* w1    = (const float*)d_in[1];
    const float* gamma = (const float*)d_in[2];
    const float* beta  = (const float*)d_in[3];
    const float* mean  = (const float*)d_in[4];
    const float* var   = (const float*)d_in[5];
    const float* w2    = (const float*)d_in[6];
    const float* b2    = (const float*)d_in[7];

    float* out    = (float*)d_out;
    float* vout   = out;                 // [32,768]
    float* score  = out + BB * CC;       // [32,1024]

    float* h      = (float*)d_ws;                        // [32,96,1024]
    float* weight = h + (size_t)BB * HID * NPIX;         // [32,1024]

    k1_gemm_bn_relu<<<dim3(16, BB), 256, 0, stream>>>(x, w1, gamma, beta, mean, var, h);
    k2_conv3x3<<<BB, 256, 0, stream>>>(h, w2, b2, score);
    k3_topk_softmax<<<BB, 256, 0, stream>>>(score, weight);
    k4_weighted_sum<<<BB * (CC / 4), 256, 0, stream>>>(x, weight, vout);
}

// Round 2
// 91.231 us; speedup vs baseline: 1.9390x; 1.9390x over previous
//
#include <hip/hip_runtime.h>
#include <math.h>

#define BB 32
#define CC 768
#define HID 96
#define NPIX 1024
#define KSEL 256
#define BN_EPS_F 1e-5f

typedef __bf16 bf16x8 __attribute__((ext_vector_type(8)));
typedef float f32x4 __attribute__((ext_vector_type(4)));

__device__ __forceinline__ unsigned short f2bf(float f) {
    unsigned u = __float_as_uint(f);
    return (unsigned short)((u + 0x7FFFu + ((u >> 16) & 1u)) >> 16);  // RNE
}
__device__ __forceinline__ unsigned pack2(float lo, float hi) {
    return (unsigned)f2bf(lo) | ((unsigned)f2bf(hi) << 16);
}

// ---------------------------------------------------------------------------
// K0: prep — w1 f32 -> bf16 [96][768]; BN scale/shift [96].
// grid 73 x 256.
// ---------------------------------------------------------------------------
__global__ __launch_bounds__(256) void k0_prep(
    const float* __restrict__ w1, const float* __restrict__ gamma,
    const float* __restrict__ beta, const float* __restrict__ mean,
    const float* __restrict__ var,
    unsigned short* __restrict__ w1b, float* __restrict__ scale,
    float* __restrict__ shift)
{
    int t = threadIdx.x, bk = blockIdx.x;
    if (bk < 72) {
        int idx = (bk * 256 + t) * 4;           // 0..73724
        float4 v = *reinterpret_cast<const float4*>(w1 + idx);
        uint2 o;
        o.x = pack2(v.x, v.y);
        o.y = pack2(v.z, v.w);
        *reinterpret_cast<uint2*>(w1b + idx) = o;
    } else if (t < HID) {
        float sc = gamma[t] * rsqrtf(var[t] + BN_EPS_F);
        scale[t] = sc;
        shift[t] = beta[t] - mean[t] * sc;
    }
}

// ---------------------------------------------------------------------------
// K1: bf16 MFMA GEMM  H[o,n] = sum_c w1[o,c]*x[b,c,n], fused BN+ReLU.
// grid (16 n-tiles of 64, 32 b), 256 thr = 4 waves; wave w owns n-16-tile w.
// K-chunk 64. x converted f32->bf16 during staging (k-pairs packed in uint).
// ---------------------------------------------------------------------------
__global__ __launch_bounds__(256) void k1_gemm_mfma(
    const float* __restrict__ x, const unsigned short* __restrict__ w1b,
    const float* __restrict__ scale, const float* __restrict__ shift,
    float* __restrict__ h_out)
{
    __shared__ unsigned short W1s[96][72];  // [o][k] bf16, stride 72 (144B, 16B-mult)
    __shared__ unsigned Xs[32][68];         // [kpair][n] uint=2 bf16, stride 272B
    __shared__ float sc_s[HID], sh_s[HID];

    const int t = threadIdx.x;
    const int b = blockIdx.y;
    const int n0 = blockIdx.x * 64;
    const int wave = t >> 6, lane = t & 63;
    const int lm = lane & 15, g = lane >> 4;
    const int nl = wave * 16 + lm;

    if (t < HID) { sc_s[t] = scale[t]; sh_s[t] = shift[t]; }

    f32x4 acc[6];
#pragma unroll
    for (int mt = 0; mt < 6; ++mt) acc[mt] = (f32x4){0.f, 0.f, 0.f, 0.f};

    const int kp = t >> 3, q = t & 7;
    const float* xbase = x + ((size_t)b * CC) * NPIX + n0;

    for (int c0 = 0; c0 < CC; c0 += 64) {
        __syncthreads();
        // stage X: rows c0..c0+63 -> Xs[kp][n] packed bf16 pairs
        {
            const float* r0 = xbase + (size_t)(c0 + 2 * kp) * NPIX;
            const float* r1 = r0 + NPIX;
#pragma unroll
            for (int i2 = 0; i2 < 2; ++i2) {
                int noff = q * 4 + i2 * 32;
                float4 a4 = *reinterpret_cast<const float4*>(r0 + noff);
                float4 b4 = *reinterpret_cast<const float4*>(r1 + noff);
                uint4 pk;
                pk.x = pack2(a4.x, b4.x);
                pk.y = pack2(a4.y, b4.y);
                pk.z = pack2(a4.z, b4.z);
                pk.w = pack2(a4.w, b4.w);
                *reinterpret_cast<uint4*>(&Xs[kp][noff]) = pk;
            }
        }
        // stage W1: [96][c0..c0+63]
#pragma unroll
        for (int i = 0; i < 3; ++i) {
            int idx = t + i * 256;              // 0..767
            int m = idx >> 3, ko = (idx & 7) * 8;
            uint4 wv = *reinterpret_cast<const uint4*>(w1b + (size_t)m * CC + c0 + ko);
            *reinterpret_cast<uint4*>(&W1s[m][ko]) = wv;
        }
        __syncthreads();

#pragma unroll
        for (int half = 0; half < 2; ++half) {
            uint4 bu;
            bu.x = Xs[16 * half + 4 * g + 0][nl];
            bu.y = Xs[16 * half + 4 * g + 1][nl];
            bu.z = Xs[16 * half + 4 * g + 2][nl];
            bu.w = Xs[16 * half + 4 * g + 3][nl];
            bf16x8 bfr = __builtin_bit_cast(bf16x8, bu);
#pragma unroll
            for (int mt = 0; mt < 6; ++mt) {
                uint4 au = *reinterpret_cast<const uint4*>(
                    &W1s[mt * 16 + lm][half * 32 + g * 8]);
                acc[mt] = __builtin_amdgcn_mfma_f32_16x16x32_bf16(
                    __builtin_bit_cast(bf16x8, au), bfr, acc[mt], 0, 0, 0);
            }
        }
    }

    // epilogue: C/D layout col=lane&15 (n), row=g*4+reg (o); BN+ReLU
#pragma unroll
    for (int mt = 0; mt < 6; ++mt) {
#pragma unroll
        for (int r = 0; r < 4; ++r) {
            int o = mt * 16 + g * 4 + r;
            float v = fmaxf(acc[mt][r] * sc_s[o] + sh_s[o], 0.f);
            h_out[((size_t)b * HID + o) * NPIX + n0 + nl] = v;
        }
    }
}

// ---------------------------------------------------------------------------
// K2: 3x3 conv HID->1, SAME. grid (4 row-tiles, 32 b), 256 thr, 1 px/thread.
// Channels staged in chunks of 16 with row halo.
// ---------------------------------------------------------------------------
__global__ __launch_bounds__(256) void k2_conv3x3(
    const float* __restrict__ h_in, const float* __restrict__ w2,
    const float* __restrict__ b2, float* __restrict__ score_out)
{
    __shared__ float hs[16][10][34];
    __shared__ float w2s[HID][9];

    const int t = threadIdx.x;
    const int ry = blockIdx.x, b = blockIdx.y;
    const int y = t >> 5, xx = t & 31;      // local pixel
    const int Y = ry * 8 + y;

    for (int i = t; i < 16 * 10 * 34; i += 256) ((float*)hs)[i] = 0.f;
    for (int i = t; i < HID * 9; i += 256) ((float*)w2s)[i] = w2[i];

    const float* hb = h_in + (size_t)b * HID * NPIX;
    float acc = 0.f;

    for (int c0 = 0; c0 < HID; c0 += 16) {
        __syncthreads();
#pragma unroll
        for (int i = 0; i < 20; ++i) {
            int idx = t + i * 256;           // 0..5119
            int col = idx & 31, row = (idx >> 5) % 10, ch = idx / 320;
            int Ya = ry * 8 - 1 + row;
            if (Ya >= 0 && Ya < 32)
                hs[ch][row][col + 1] = hb[(size_t)(c0 + ch) * NPIX + Ya * 32 + col];
        }
        __syncthreads();
#pragma unroll
        for (int ch = 0; ch < 16; ++ch) {
            float s = 0.f;
#pragma unroll
            for (int ky = 0; ky < 3; ++ky)
#pragma unroll
                for (int kx = 0; kx < 3; ++kx)
                    s += hs[ch][y + ky][xx + kx] * w2s[c0 + ch][ky * 3 + kx];
            acc += s;
        }
    }
    score_out[b * NPIX + Y * 32 + xx] = acc + b2[0];
}

// ---------------------------------------------------------------------------
// K3: exact top-256 (radix select, first-index tie-break) + softmax ->
// dense weight[1024]. grid 32, 256 thr; elements register-resident (4/thr).
// ---------------------------------------------------------------------------
__global__ __launch_bounds__(256) void k3_topk_softmax(
    const float* __restrict__ score, float* __restrict__ weight)
{
    __shared__ unsigned hist[256];
    __shared__ unsigned wtot[4];
    __shared__ unsigned pcnt16[16];
    __shared__ float redf[4];
    __shared__ unsigned sh_bin, sh_rem;

    const int t = threadIdx.x, b = blockIdx.x;
    const int lane = t & 63, wv = t >> 6;

    float fvals[4];
    unsigned uvals[4];
#pragma unroll
    for (int i = 0; i < 4; ++i) {
        float f = score[b * NPIX + t + 256 * i];
        fvals[i] = f;
        unsigned u = __float_as_uint(f);
        uvals[i] = (u & 0x80000000u) ? ~u : (u | 0x80000000u);
    }

    unsigned prefix = 0, rem = KSEL;
    for (int p = 3; p >= 0; --p) {
        hist[t] = 0;
        __syncthreads();
        const int sh_hi = (p + 1) * 8;
#pragma unroll
        for (int i = 0; i < 4; ++i) {
            unsigned u = uvals[i];
            bool match = (p == 3) || ((u >> sh_hi) == (prefix >> sh_hi));
            if (match) atomicAdd(&hist[(u >> (p * 8)) & 0xffu], 1u);
        }
        __syncthreads();
        unsigned own = hist[t];
        unsigned val = own;
#pragma unroll
        for (int off = 1; off <= 32; off <<= 1) {
            unsigned o2 = __shfl_down(val, off);
            if (lane + off < 64) val += o2;
        }
        if (lane == 0) wtot[wv] = val;
        __syncthreads();
        unsigned suff = val;
        for (int w = wv + 1; w < 4; ++w) suff += wtot[w];
        unsigned nexts = suff - own;        // count with bin > t
        if (suff >= rem && nexts < rem) { sh_bin = (unsigned)t; sh_rem = rem - nexts; }
        __syncthreads();
        prefix |= (sh_bin << (p * 8));
        rem = sh_rem;
        __syncthreads();
    }
    const unsigned T = prefix, need = rem;

    // global max for softmax stability
    float m = -INFINITY;
#pragma unroll
    for (int i = 0; i < 4; ++i) m = fmaxf(m, fvals[i]);
#pragma unroll
    for (int off = 32; off >= 1; off >>= 1) m = fmaxf(m, __shfl_xor(m, off));
    if (lane == 0) redf[wv] = m;
    __syncthreads();
    m = fmaxf(fmaxf(redf[0], redf[1]), fmaxf(redf[2], redf[3]));

    // rank equals by ascending index n = i*256 + wv*64 + lane
    unsigned lp[4]; bool eqf[4], gtf[4];
    unsigned long long lmask = (1ULL << lane) - 1ULL;
#pragma unroll
    for (int i = 0; i < 4; ++i) {
        bool eq = (uvals[i] == T);
        eqf[i] = eq; gtf[i] = (uvals[i] > T);
        unsigned long long mk = __ballot(eq);
        lp[i] = (unsigned)__popcll(mk & lmask);
        if (lane == 0) pcnt16[i * 4 + wv] = (unsigned)__popcll(mk);
    }
    __syncthreads();
    unsigned cum = 0, baseArr[4];
#pragma unroll
    for (int ii = 0; ii < 4; ++ii) {
        unsigned b0 = cum;
        for (int w = 0; w < wv; ++w) b0 += pcnt16[ii * 4 + w];
        baseArr[ii] = b0;
        for (int w = 0; w < 4; ++w) cum += pcnt16[ii * 4 + w];
    }
    float evals[4], sumExp = 0.f;
#pragma unroll
    for (int i = 0; i < 4; ++i) {
        bool sel = gtf[i] || (eqf[i] && (baseArr[i] + lp[i]) < need);
        float e = sel ? expf(fvals[i] - m) : 0.f;
        evals[i] = e;
        sumExp += e;
    }
#pragma unroll
    for (int off = 32; off >= 1; off >>= 1) sumExp += __shfl_xor(sumExp, off);
    if (lane == 0) redf[wv] = sumExp;
    __syncthreads();
    float inv = 1.0f / (redf[0] + redf[1] + redf[2] + redf[3]);
#pragma unroll
    for (int i = 0; i < 4; ++i)
        weight[b * NPIX + i * 256 + t] = evals[i] * inv;
}

// ---------------------------------------------------------------------------
// K4: v[b,c] = sum_n x[b,c,n]*weight[b,n]. grid 32*192, 4 waves, 1 c/wave.
// ---------------------------------------------------------------------------
__global__ __launch_bounds__(256) void k4_weighted_sum(
    const float* __restrict__ x, const float* __restrict__ weight,
    float* __restrict__ v)
{
    __shared__ float wsm[NPIX];
    const int t = threadIdx.x;
    const int b = blockIdx.x / 192, cg = blockIdx.x % 192;

    *reinterpret_cast<float4*>(&wsm[t * 4]) =
        *reinterpret_cast<const float4*>(&weight[b * NPIX + t * 4]);
    __syncthreads();

    const int lane = t & 63, wvv = t >> 6;
    const int c = cg * 4 + wvv;
    const float* xr = x + ((size_t)b * CC + c) * NPIX;

    float acc = 0.f;
#pragma unroll
    for (int j = 0; j < 4; ++j) {
        int off = j * 256 + lane * 4;
        float4 xv = *reinterpret_cast<const float4*>(xr + off);
        float4 wv4 = *reinterpret_cast<const float4*>(&wsm[off]);
        acc += xv.x * wv4.x + xv.y * wv4.y + xv.z * wv4.z + xv.w * wv4.w;
    }
#pragma unroll
    for (int off = 32; off >= 1; off >>= 1) acc += __shfl_xor(acc, off);
    if (lane == 0) v[(size_t)b * CC + c] = acc;
}

// ---------------------------------------------------------------------------
extern "C" void kernel_launch(void* const* d_in, const int* in_sizes, int n_in,
                              void* d_out, int out_size, void* d_ws, size_t ws_size,
                              hipStream_t stream)
{
    const float* x     = (const float*)d_in[0];
    const float* w1    = (const float*)d_in[1];
    const float* gamma = (const float*)d_in[2];
    const float* beta  = (const float*)d_in[3];
    const float* mean  = (const float*)d_in[4];
    const float* var   = (const float*)d_in[5];
    const float* w2    = (const float*)d_in[6];
    const float* b2    = (const float*)d_in[7];

    float* out   = (float*)d_out;
    float* vout  = out;                  // [32,768]
    float* score = out + BB * CC;        // [32,1024]

    float* h       = (float*)d_ws;                           // 32*96*1024 f32
    float* weight  = h + (size_t)BB * HID * NPIX;            // 32*1024 f32
    unsigned short* w1b = (unsigned short*)(weight + BB * NPIX);  // 96*768 bf16
    float* scale   = (float*)(w1b + HID * CC);               // 96
    float* shift   = scale + HID;                            // 96

    k0_prep<<<73, 256, 0, stream>>>(w1, gamma, beta, mean, var, w1b, scale, shift);
    k1_gemm_mfma<<<dim3(16, BB), 256, 0, stream>>>(x, w1b, scale, shift, h);
    k2_conv3x3<<<dim3(4, BB), 256, 0, stream>>>(h, w2, b2, score);
    k3_topk_softmax<<<BB, 256, 0, stream>>>(score, weight);
    k4_weighted_sum<<<BB * (CC / 4), 256, 0, stream>>>(x, weight, vout);
}